// Round 15
// baseline (33.487 us; speedup 1.0000x reference)
//
#include <hip/hip_runtime.h>
#include <hip/hip_bf16.h>

#define MM 4096
#define NN 512
#define RR 32

__device__ __forceinline__ float softplus_f(float x) {
    return x > 20.0f ? x : log1pf(__expf(x));
}

__device__ __forceinline__ int bitrev6(int l) {
    return ((l & 1) << 5) | ((l & 2) << 3) | ((l & 4) << 1) |
           ((l & 8) >> 1) | ((l & 16) >> 3) | ((l & 32) >> 5);
}

// In-register 64-point DIF FFT across the 64 lanes of a wave.
__device__ __forceinline__ void wave_fft64(float& xr, float& xi) {
#pragma unroll
    for (int s = 32; s >= 1; s >>= 1) {
        const float pr = __shfl_xor(xr, s, 64);
        const float pi = __shfl_xor(xi, s, 64);
        const int   lane = threadIdx.x & 63;
        const bool  hi = (lane & s) != 0;
        const float ur = xr + pr, ui = xi + pi;
        const float vr = pr - xr, vi = pi - xi;
        const int   j  = lane & (s - 1);
        const float rev = (float)j * (1.0f / (float)(2 * s));   // [0, 0.5)
        const float ct = __builtin_amdgcn_cosf(rev);
        const float st = __builtin_amdgcn_sinf(rev);
        const float wr = fmaf(vr, ct,   vi * st);   // v * (ct - i st)
        const float wi = fmaf(vi, ct, -(vr * st));
        xr = hi ? wr : ur;
        xi = hi ? wi : ui;
    }
}

// ---------------------------------------------------------------------------
// FFT step 1 (proven): FFT-64 over n2, twiddle, transposed store.
// ---------------------------------------------------------------------------
__global__ __launch_bounds__(256) void fft64_step1(const float* __restrict__ H,
                                                   float2* __restrict__ zbuf) {
    const int wave = (blockIdx.x * 256 + threadIdx.x) >> 6;   // 0..2047
    const int lane = threadIdx.x & 63;                        // n2
    const int d    = wave >> 6;                               // 0..31
    const int n1   = wave & 63;                               // 0..63
    float xr = softplus_f(H[(size_t)d * MM + n1 + 64 * lane]);
    float xi = 0.0f;
    wave_fft64(xr, xi);
    const int k2 = bitrev6(lane);
    const float rev = (float)(n1 * k2) * (1.0f / 4096.0f);    // [0,1)
    const float ct = __builtin_amdgcn_cosf(rev);
    const float st = __builtin_amdgcn_sinf(rev);
    zbuf[(size_t)d * MM + k2 * 64 + n1] =
        make_float2(fmaf(xr, ct, xi * st), fmaf(xi, ct, -(xr * st)));
}

// ---------------------------------------------------------------------------
// FFT step 2 (proven): FFT-64 over n1 (contiguous), scatter.
// ---------------------------------------------------------------------------
__global__ __launch_bounds__(256) void fft64_step2(const float2* __restrict__ zbuf,
                                                   float2* __restrict__ hft) {
    const int wave = (blockIdx.x * 256 + threadIdx.x) >> 6;
    const int lane = threadIdx.x & 63;                        // n1
    const int d    = wave >> 6;
    const int k2   = wave & 63;
    const float2 z = zbuf[(size_t)d * MM + k2 * 64 + lane];
    float xr = z.x, xi = z.y;
    wave_fft64(xr, xi);
    hft[(size_t)d * MM + k2 + 64 * bitrev6(lane)] = make_float2(xr, xi);
}

// ---------------------------------------------------------------------------
// Main kernel — COMBINED: 8 waves/SIMD + 2 LDS instrs/(t,d) + conflict-free
// bank pattern (the three walls of R8/R12/R14, fixed simultaneously):
//  * K=2 consecutive m per thread (+2 Hermitian) -> 524288 threads = 8192
//    waves = 8/SIMD. Grid (2048/64, 512/16) = (32,32) = 1024 blocks,
//    4 blocks/CU (LDS 24.3 KB/block -> 97 KB/CU).
//  * htile[d][ml] read: lane ml -> float4 index ml -> contiguous 16B/lane,
//    banks 4*ml..4*ml+3: all 32 banks covered by 8 lanes (optimal).
//    (R14 read even-indexed float4s -> 8 banks only -> ~16-way serialize.)
//  * params packed in one broadcast ds_read_b128.
//  * __launch_bounds__(512, 8) caps VGPR at 64 for full occupancy.
// Math identical to R6/R8/R12/R14-proven Hermitian formulation.
// ---------------------------------------------------------------------------
__global__ __launch_bounds__(512, 8) void shiftnmf_real(const float* __restrict__ W,
                                                        const float* __restrict__ tau,
                                                        const float2* __restrict__ hft,
                                                        float* __restrict__ out) {
    __shared__ float4 htile[RR][32];    // 16 KB: 64 float2 (= 32 float4) per d
    __shared__ float4 pw_s[16][RR];     // 8 KB: (A, tf, ru, iu) per (row, d)
    __shared__ float  h2048_s[RR];

    const int tid = threadIdx.x;
    const int mb  = blockIdx.x * 64;       // [0, 2048)
    const int nb  = blockIdx.y * 16;

    {   // per-(row,d) params: 512 threads cover 16 x 32 exactly
        const int nl = tid >> 5;
        const int dd = tid & 31;
        const float w = W[(size_t)(nb + nl) * RR + dd];
        const float t = tau[(size_t)(nb + nl) * RR + dd];
        const float tf = t * (1.0f / (float)MM);
        const float fr = t - floorf(t);                        // frac(tau)
        pw_s[nl][dd] = make_float4(softplus_f(w), tf,
                                   __builtin_amdgcn_cosf(fr),   // ru
                                   -__builtin_amdgcn_sinf(fr)); // iu
    }
    {   // stage Hft tile: 32 rows x 32 float4 = 1024 float4, 2 per thread
        float4* hf4 = &htile[0][0];
#pragma unroll
        for (int j = 0; j < 2; ++j) {
            const int idx = tid + 512 * j;          // [0, 1024)
            const int r   = idx >> 5;               // d row 0..31
            const int c   = idx & 31;               // float4 col 0..31
            hf4[idx] = ((const float4*)(hft + (size_t)r * MM + mb))[c];
        }
    }
    if (tid < RR) h2048_s[tid] = hft[(size_t)tid * MM + 2048].x;
    __syncthreads();

    const int g  = tid >> 5;                // row 0..15
    const int ml = tid & 31;
    const int n  = nb + g;
    const int m0 = mb + 2 * ml;             // [0, 2046], even
    const float m0f = (float)m0;

    float accm0 = 0.f, accm1 = 0.f, accp0 = 0.f, accp1 = 0.f;

    for (int d = 0; d < RR; ++d) {
        const float4 P = pw_s[g][d];        // broadcast ds_read_b128
        const float A  = P.x;
        const float tf = P.y;
        const float ru = P.z;
        const float iu = P.w;

        float r0 = tf * m0f;  r0 -= floorf(r0);        // [0,1)
        const float c0 = __builtin_amdgcn_cosf(r0);
        const float s0 = __builtin_amdgcn_sinf(r0);
        float dl = tf - floorf(tf);                    // 1-step rotator
        const float cd = __builtin_amdgcn_cosf(dl);
        const float sd = __builtin_amdgcn_sinf(dl);
        const float ca = A * c0, sa = A * s0;          // phasor at m0
        const float cb = ca * cd - sa * sd;            // phasor at m0+1
        const float sb = sa * cd + ca * sd;

        const float4 q = htile[d][ml];      // contiguous ds_read_b128:
                                            // h[m0]=(q.x,q.y), h[m0+1]=(q.z,q.w)
        {
            const float rz = fmaf(ca, q.x,   sa * q.y);
            const float iz = fmaf(ca, q.y, -(sa * q.x));
            accm0 += rz;
            accp0  = fmaf(ru, rz, fmaf(iu, iz, accp0));
        }
        {
            const float rz = fmaf(cb, q.z,   sb * q.w);
            const float iz = fmaf(cb, q.w, -(sb * q.z));
            accm1 += rz;
            accp1  = fmaf(ru, rz, fmaf(iu, iz, accp1));
        }
    }

    float* orow = out + (size_t)n * MM;
    *(float2*)(orow + m0) = make_float2(accm0, accm1);   // m0 even, 8B-aligned
    if (m0 != 0) {
        orow[MM - m0]     = accp0;          // [2050, 4095]
        orow[MM - m0 - 1] = accp1;
    } else {
        orow[MM - 1] = accp1;               // skip m=0 self-mirror
    }

    // Nyquist column m = 2048 (real bin): one lane per row, bx==0 blocks.
    if (blockIdx.x == 0 && ml == 0) {
        float acc = 0.0f;
        for (int d = 0; d < RR; ++d) {
            const float4 P = pw_s[g][d];
            float r = P.y * 2048.0f;
            r -= floorf(r);
            acc = fmaf(P.x * h2048_s[d], __builtin_amdgcn_cosf(r), acc);
        }
        orow[2048] = acc;
    }
}

// ---------------------------------------------------------------------------
// Complex-output hedge path (never taken in practice): R5-proven kernel.
// ---------------------------------------------------------------------------
__global__ __launch_bounds__(256) void shiftnmf_cplx(const float* __restrict__ W,
                                                     const float* __restrict__ tau,
                                                     const float2* __restrict__ hft,
                                                     float* __restrict__ out) {
    __shared__ float spw_s[16][RR];
    __shared__ float tau_s[16][RR];
    const int tid = threadIdx.x;
    const int mb  = blockIdx.x * 256;
    const int nb  = blockIdx.y * 16;
    for (int idx = tid; idx < 16 * RR; idx += 256) {
        const int nl = idx >> 5;
        const int dd = idx & 31;
        spw_s[nl][dd] = softplus_f(W[(size_t)(nb + nl) * RR + dd]);
        tau_s[nl][dd] = tau[(size_t)(nb + nl) * RR + dd] * (1.0f / (float)MM);
    }
    __syncthreads();
    const int g  = tid >> 5;
    const int ml = tid & 31;
    const int n0 = g * 2;
    const float m0f = (float)(mb + ml);
    const float2* hcol = hft + mb + ml;
    float accR[2][8], accI[2][8];
#pragma unroll
    for (int j = 0; j < 2; ++j)
#pragma unroll
        for (int k = 0; k < 8; ++k) { accR[j][k] = 0.0f; accI[j][k] = 0.0f; }
    float2 hc[8], hn[8];
#pragma unroll
    for (int k = 0; k < 8; ++k) hc[k] = hcol[32 * k];
    for (int d = 0; d < RR; ++d) {
        const float2* hnp = hcol + (size_t)((d + 1 < RR) ? d + 1 : d) * MM;
#pragma unroll
        for (int k = 0; k < 8; ++k) hn[k] = hnp[32 * k];
#pragma unroll
        for (int j = 0; j < 2; ++j) {
            const float A  = spw_s[n0 + j][d];
            const float tf = tau_s[n0 + j][d];
            float r0 = tf * m0f;  r0 -= floorf(r0);
            float dl = tf * 32.0f; dl -= floorf(dl);
            const float c0 = __builtin_amdgcn_cosf(r0);
            const float s0 = __builtin_amdgcn_sinf(r0);
            const float cd = __builtin_amdgcn_cosf(dl);
            const float sd = __builtin_amdgcn_sinf(dl);
            float ca = A * c0, sa = A * s0;
            float cb = ca * cd - sa * sd;
            float sb = sa * cd + ca * sd;
            const float c2 = fmaf(-2.0f * sd, sd, 1.0f);
            const float s2 = 2.0f * sd * cd;
#pragma unroll
            for (int t4 = 0; t4 < 4; ++t4) {
                const float2 h0 = hc[2 * t4];
                const float2 h1 = hc[2 * t4 + 1];
                accR[j][2*t4]   = fmaf(ca, h0.x, fmaf(sa, h0.y, accR[j][2*t4]));
                accR[j][2*t4+1] = fmaf(cb, h1.x, fmaf(sb, h1.y, accR[j][2*t4+1]));
                accI[j][2*t4]   = fmaf(ca, h0.y, fmaf(-sa, h0.x, accI[j][2*t4]));
                accI[j][2*t4+1] = fmaf(cb, h1.y, fmaf(-sb, h1.x, accI[j][2*t4+1]));
                if (t4 < 3) {
                    const float can = fmaf(ca, c2, -(sa * s2));
                    const float san = fmaf(sa, c2,  (ca * s2));
                    const float cbn = fmaf(cb, c2, -(sb * s2));
                    const float sbn = fmaf(sb, c2,  (cb * s2));
                    ca = can; sa = san; cb = cbn; sb = sbn;
                }
            }
        }
#pragma unroll
        for (int k = 0; k < 8; ++k) hc[k] = hn[k];
    }
#pragma unroll
    for (int j = 0; j < 2; ++j) {
        float2* orow = (float2*)out + (size_t)(nb + n0 + j) * MM + mb + ml;
#pragma unroll
        for (int k = 0; k < 8; ++k)
            orow[32 * k] = make_float2(accR[j][k], accI[j][k]);
    }
}

extern "C" void kernel_launch(void* const* d_in, const int* in_sizes, int n_in,
                              void* d_out, int out_size, void* d_ws, size_t ws_size,
                              hipStream_t stream) {
    const float* W   = (const float*)d_in[0];   // (512, 32)
    const float* H   = (const float*)d_in[1];   // (32, 4096)
    const float* tau = (const float*)d_in[2];   // (512, 32)

    const size_t hft_bytes = (size_t)RR * MM * sizeof(float2);  // 1 MB
    if (ws_size < 2 * hft_bytes) return;        // safe bail (no crash)
    float2* zbuf = (float2*)d_ws;               // step-1 intermediate (1 MB)
    float2* hft  = zbuf + (size_t)RR * MM;      // spectrum (1 MB)

    fft64_step1<<<512, 256, 0, stream>>>(H, zbuf);
    fft64_step2<<<512, 256, 0, stream>>>(zbuf, hft);

    if (out_size >= 2 * NN * MM) {
        dim3 grid(MM / 256, NN / 16);
        shiftnmf_cplx<<<grid, 256, 0, stream>>>(W, tau, hft, (float*)d_out);
    } else {
        dim3 grid(2048 / 64, NN / 16);
        shiftnmf_real<<<grid, 512, 0, stream>>>(W, tau, hft, (float*)d_out);
    }
}

// Round 16
// 31.516 us; speedup vs baseline: 1.0625x; 1.0625x over previous
//
#include <hip/hip_runtime.h>
#include <hip/hip_bf16.h>

#define MM 4096
#define NN 512
#define RR 32

__device__ __forceinline__ float softplus_f(float x) {
    return x > 20.0f ? x : log1pf(__expf(x));
}

__device__ __forceinline__ int bitrev6(int l) {
    return ((l & 1) << 5) | ((l & 2) << 3) | ((l & 4) << 1) |
           ((l & 8) >> 1) | ((l & 16) >> 3) | ((l & 32) >> 5);
}

// In-register 64-point DIF FFT across the 64 lanes of a wave.
__device__ __forceinline__ void wave_fft64(float& xr, float& xi) {
#pragma unroll
    for (int s = 32; s >= 1; s >>= 1) {
        const float pr = __shfl_xor(xr, s, 64);
        const float pi = __shfl_xor(xi, s, 64);
        const int   lane = threadIdx.x & 63;
        const bool  hi = (lane & s) != 0;
        const float ur = xr + pr, ui = xi + pi;
        const float vr = pr - xr, vi = pi - xi;
        const int   j  = lane & (s - 1);
        const float rev = (float)j * (1.0f / (float)(2 * s));   // [0, 0.5)
        const float ct = __builtin_amdgcn_cosf(rev);
        const float st = __builtin_amdgcn_sinf(rev);
        const float wr = fmaf(vr, ct,   vi * st);   // v * (ct - i st)
        const float wi = fmaf(vi, ct, -(vr * st));
        xr = hi ? wr : ur;
        xi = hi ? wi : ui;
    }
}

// ---------------------------------------------------------------------------
// FFT step 1 (proven): FFT-64 over n2, twiddle, transposed store.
// ---------------------------------------------------------------------------
__global__ __launch_bounds__(256) void fft64_step1(const float* __restrict__ H,
                                                   float2* __restrict__ zbuf) {
    const int wave = (blockIdx.x * 256 + threadIdx.x) >> 6;   // 0..2047
    const int lane = threadIdx.x & 63;                        // n2
    const int d    = wave >> 6;                               // 0..31
    const int n1   = wave & 63;                               // 0..63
    float xr = softplus_f(H[(size_t)d * MM + n1 + 64 * lane]);
    float xi = 0.0f;
    wave_fft64(xr, xi);
    const int k2 = bitrev6(lane);
    const float rev = (float)(n1 * k2) * (1.0f / 4096.0f);    // [0,1)
    const float ct = __builtin_amdgcn_cosf(rev);
    const float st = __builtin_amdgcn_sinf(rev);
    zbuf[(size_t)d * MM + k2 * 64 + n1] =
        make_float2(fmaf(xr, ct, xi * st), fmaf(xi, ct, -(xr * st)));
}

// ---------------------------------------------------------------------------
// FFT step 2 (proven): FFT-64 over n1 (contiguous), scatter.
// ---------------------------------------------------------------------------
__global__ __launch_bounds__(256) void fft64_step2(const float2* __restrict__ zbuf,
                                                   float2* __restrict__ hft) {
    const int wave = (blockIdx.x * 256 + threadIdx.x) >> 6;
    const int lane = threadIdx.x & 63;                        // n1
    const int d    = wave >> 6;
    const int k2   = wave & 63;
    const float2 z = zbuf[(size_t)d * MM + k2 * 64 + lane];
    float xr = z.x, xi = z.y;
    wave_fft64(xr, xi);
    hft[(size_t)d * MM + k2 + 64 * bitrev6(lane)] = make_float2(xr, xi);
}

// ---------------------------------------------------------------------------
// Main kernel — R6-proven K=8 dual-phasor Hermitian body, with the
// d-reduction SPLIT across two thread-halves (d=0..15 / d=16..31):
//   * per-output VALU work and trans/SIMD identical to R6 (the most
//     efficient body measured), but waves double: 512 blocks x 512 thr
//     = 4096 waves = 4 waves/SIMD (R6 ran this body at 2).
//   * halves combine via one LDS pass: red[k][g][ml] (16 KB, conflict-free
//     per-k contiguous lanes), one barrier, half 0 sums and stores.
// Block: 512 thr = 2 halves x (8 rows x 32 lanes); tile 8 n x 256 m(half).
// Grid (2048/256, 512/8) = (8, 64) = 512 blocks.
// ---------------------------------------------------------------------------
__global__ __launch_bounds__(512, 4) void shiftnmf_real(const float* __restrict__ W,
                                                        const float* __restrict__ tau,
                                                        const float2* __restrict__ hft,
                                                        float* __restrict__ out) {
    __shared__ float spw_s[8][RR];
    __shared__ float tf_s[8][RR];
    __shared__ float cu_s[8][RR];
    __shared__ float su_s[8][RR];
    __shared__ float h2048_s[RR];
    __shared__ float red[16][8][32];    // 16 KB: [k][row][lane] partials

    const int tid = threadIdx.x;
    const int mb  = blockIdx.x * 256;      // [0, 2048)
    const int nb  = blockIdx.y * 8;

    if (tid < 256) {   // per-(row,d) params: 256 threads cover 8 x 32
        const int nl = tid >> 5;
        const int dd = tid & 31;
        const float w = W[(size_t)(nb + nl) * RR + dd];
        const float t = tau[(size_t)(nb + nl) * RR + dd];
        spw_s[nl][dd] = softplus_f(w);
        tf_s[nl][dd]  = t * (1.0f / (float)MM);
        const float fr = t - floorf(t);                // frac(tau)
        cu_s[nl][dd] =  __builtin_amdgcn_cosf(fr);     // Re e^{-2pi i tau}
        su_s[nl][dd] = -__builtin_amdgcn_sinf(fr);     // Im e^{-2pi i tau}
    }
    if (tid < RR) h2048_s[tid] = hft[(size_t)tid * MM + 2048].x;
    __syncthreads();

    const int half = tid >> 8;              // 0 or 1
    const int t8   = tid & 255;
    const int g    = t8 >> 5;               // row 0..7
    const int ml   = t8 & 31;
    const int n    = nb + g;
    const int d0   = half * 16;             // this half's d range: d0..d0+15
    const float m0f = (float)(mb + ml);
    const float2* hcol = hft + mb + ml;

    float accm[8], accp[8];
#pragma unroll
    for (int k = 0; k < 8; ++k) { accm[k] = 0.0f; accp[k] = 0.0f; }

    float2 hc[8], hn[8];
#pragma unroll
    for (int k = 0; k < 8; ++k) hc[k] = hcol[(size_t)d0 * MM + 32 * k];

    for (int i = 0; i < 16; ++i) {
        const int d = d0 + i;
        const int dnx = (i < 15) ? d + 1 : d;
        const float2* hnp = hcol + (size_t)dnx * MM;
#pragma unroll
        for (int k = 0; k < 8; ++k) hn[k] = hnp[32 * k];

        const float A  = spw_s[g][d];
        const float tf = tf_s[g][d];
        const float ru = cu_s[g][d];
        const float iu = su_s[g][d];

        float r0 = tf * m0f;   r0 -= floorf(r0);
        float dl = tf * 32.0f; dl -= floorf(dl);
        const float c0 = __builtin_amdgcn_cosf(r0);
        const float s0 = __builtin_amdgcn_sinf(r0);
        const float cd = __builtin_amdgcn_cosf(dl);
        const float sd = __builtin_amdgcn_sinf(dl);
        float ca = A * c0, sa = A * s0;               // phasor for even k
        float cb = ca * cd - sa * sd;                 // phasor for odd k
        float sb = sa * cd + ca * sd;
        const float c2 = fmaf(-2.0f * sd, sd, 1.0f);  // rotate by 2*delta
        const float s2 = 2.0f * sd * cd;

#pragma unroll
        for (int t = 0; t < 4; ++t) {
            const float2 h0 = hc[2 * t];
            const float2 h1 = hc[2 * t + 1];
            {
                const float rz = fmaf(ca, h0.x,   sa * h0.y);
                const float iz = fmaf(ca, h0.y, -(sa * h0.x));
                accm[2 * t]     += rz;
                accp[2 * t]      = fmaf(ru, rz, fmaf(iu, iz, accp[2 * t]));
            }
            {
                const float rz = fmaf(cb, h1.x,   sb * h1.y);
                const float iz = fmaf(cb, h1.y, -(sb * h1.x));
                accm[2 * t + 1] += rz;
                accp[2 * t + 1]  = fmaf(ru, rz, fmaf(iu, iz, accp[2 * t + 1]));
            }
            if (t < 3) {
                const float can = fmaf(ca, c2, -(sa * s2));
                const float san = fmaf(sa, c2,  (ca * s2));
                const float cbn = fmaf(cb, c2, -(sb * s2));
                const float sbn = fmaf(sb, c2,  (cb * s2));
                ca = can; sa = san; cb = cbn; sb = sbn;
            }
        }
#pragma unroll
        for (int k = 0; k < 8; ++k) hc[k] = hn[k];
    }

    // half 1 deposits partials; half 0 combines and stores
    if (half == 1) {
#pragma unroll
        for (int k = 0; k < 8; ++k) {
            red[k][g][ml]     = accm[k];
            red[k + 8][g][ml] = accp[k];
        }
    }
    __syncthreads();

    if (half == 0) {
        float* orow = out + (size_t)n * MM;
#pragma unroll
        for (int k = 0; k < 8; ++k) {
            const float am = accm[k] + red[k][g][ml];
            const float ap = accp[k] + red[k + 8][g][ml];
            const int m = mb + ml + 32 * k;       // [0, 2047]
            orow[m] = am;
            if (m != 0) orow[MM - m] = ap;        // [2049, 4095]
        }

        // Nyquist column m = 2048 (real bin): one lane per row, bx==0.
        if (blockIdx.x == 0 && ml == 0) {
            float acc = 0.0f;
            for (int d = 0; d < RR; ++d) {
                float r = tf_s[g][d] * 2048.0f;
                r -= floorf(r);
                acc = fmaf(spw_s[g][d] * h2048_s[d],
                           __builtin_amdgcn_cosf(r), acc);
            }
            orow[2048] = acc;
        }
    }
}

// ---------------------------------------------------------------------------
// Complex-output hedge path (never taken in practice): R5-proven kernel.
// ---------------------------------------------------------------------------
__global__ __launch_bounds__(256) void shiftnmf_cplx(const float* __restrict__ W,
                                                     const float* __restrict__ tau,
                                                     const float2* __restrict__ hft,
                                                     float* __restrict__ out) {
    __shared__ float spw_s[16][RR];
    __shared__ float tau_s[16][RR];
    const int tid = threadIdx.x;
    const int mb  = blockIdx.x * 256;
    const int nb  = blockIdx.y * 16;
    for (int idx = tid; idx < 16 * RR; idx += 256) {
        const int nl = idx >> 5;
        const int dd = idx & 31;
        spw_s[nl][dd] = softplus_f(W[(size_t)(nb + nl) * RR + dd]);
        tau_s[nl][dd] = tau[(size_t)(nb + nl) * RR + dd] * (1.0f / (float)MM);
    }
    __syncthreads();
    const int g  = tid >> 5;
    const int ml = tid & 31;
    const int n0 = g * 2;
    const float m0f = (float)(mb + ml);
    const float2* hcol = hft + mb + ml;
    float accR[2][8], accI[2][8];
#pragma unroll
    for (int j = 0; j < 2; ++j)
#pragma unroll
        for (int k = 0; k < 8; ++k) { accR[j][k] = 0.0f; accI[j][k] = 0.0f; }
    float2 hc[8], hn[8];
#pragma unroll
    for (int k = 0; k < 8; ++k) hc[k] = hcol[32 * k];
    for (int d = 0; d < RR; ++d) {
        const float2* hnp = hcol + (size_t)((d + 1 < RR) ? d + 1 : d) * MM;
#pragma unroll
        for (int k = 0; k < 8; ++k) hn[k] = hnp[32 * k];
#pragma unroll
        for (int j = 0; j < 2; ++j) {
            const float A  = spw_s[n0 + j][d];
            const float tf = tau_s[n0 + j][d];
            float r0 = tf * m0f;  r0 -= floorf(r0);
            float dl = tf * 32.0f; dl -= floorf(dl);
            const float c0 = __builtin_amdgcn_cosf(r0);
            const float s0 = __builtin_amdgcn_sinf(r0);
            const float cd = __builtin_amdgcn_cosf(dl);
            const float sd = __builtin_amdgcn_sinf(dl);
            float ca = A * c0, sa = A * s0;
            float cb = ca * cd - sa * sd;
            float sb = sa * cd + ca * sd;
            const float c2 = fmaf(-2.0f * sd, sd, 1.0f);
            const float s2 = 2.0f * sd * cd;
#pragma unroll
            for (int t4 = 0; t4 < 4; ++t4) {
                const float2 h0 = hc[2 * t4];
                const float2 h1 = hc[2 * t4 + 1];
                accR[j][2*t4]   = fmaf(ca, h0.x, fmaf(sa, h0.y, accR[j][2*t4]));
                accR[j][2*t4+1] = fmaf(cb, h1.x, fmaf(sb, h1.y, accR[j][2*t4+1]));
                accI[j][2*t4]   = fmaf(ca, h0.y, fmaf(-sa, h0.x, accI[j][2*t4]));
                accI[j][2*t4+1] = fmaf(cb, h1.y, fmaf(-sb, h1.x, accI[j][2*t4+1]));
                if (t4 < 3) {
                    const float can = fmaf(ca, c2, -(sa * s2));
                    const float san = fmaf(sa, c2,  (ca * s2));
                    const float cbn = fmaf(cb, c2, -(sb * s2));
                    const float sbn = fmaf(sb, c2,  (cb * s2));
                    ca = can; sa = san; cb = cbn; sb = sbn;
                }
            }
        }
#pragma unroll
        for (int k = 0; k < 8; ++k) hc[k] = hn[k];
    }
#pragma unroll
    for (int j = 0; j < 2; ++j) {
        float2* orow = (float2*)out + (size_t)(nb + n0 + j) * MM + mb + ml;
#pragma unroll
        for (int k = 0; k < 8; ++k)
            orow[32 * k] = make_float2(accR[j][k], accI[j][k]);
    }
}

extern "C" void kernel_launch(void* const* d_in, const int* in_sizes, int n_in,
                              void* d_out, int out_size, void* d_ws, size_t ws_size,
                              hipStream_t stream) {
    const float* W   = (const float*)d_in[0];   // (512, 32)
    const float* H   = (const float*)d_in[1];   // (32, 4096)
    const float* tau = (const float*)d_in[2];   // (512, 32)

    const size_t hft_bytes = (size_t)RR * MM * sizeof(float2);  // 1 MB
    if (ws_size < 2 * hft_bytes) return;        // safe bail (no crash)
    float2* zbuf = (float2*)d_ws;               // step-1 intermediate (1 MB)
    float2* hft  = zbuf + (size_t)RR * MM;      // spectrum (1 MB)

    fft64_step1<<<512, 256, 0, stream>>>(H, zbuf);
    fft64_step2<<<512, 256, 0, stream>>>(zbuf, hft);

    if (out_size >= 2 * NN * MM) {
        dim3 grid(MM / 256, NN / 16);
        shiftnmf_cplx<<<grid, 256, 0, stream>>>(W, tau, hft, (float*)d_out);
    } else {
        dim3 grid(2048 / 256, NN / 8);
        shiftnmf_real<<<grid, 512, 0, stream>>>(W, tau, hft, (float*)d_out);
    }
}